// Round 7
// baseline (3614.532 us; speedup 1.0000x reference)
//
#include <hip/hip_runtime.h>
#include <hip/hip_bf16.h>

#define Bb 32
#define Tt 512
#define Ii 256
#define Hh 512
#define Oo 128
#define NG 32   // workgroups per direction in recurrence

using bf16x8 = __attribute__((ext_vector_type(8))) __bf16;
using f32x4  = __attribute__((ext_vector_type(4))) float;

__device__ __forceinline__ bf16x8 f32x8_to_bf16(const float* p) {
    const float4 u = *reinterpret_cast<const float4*>(p);
    const float4 v = *reinterpret_cast<const float4*>(p + 4);
    bf16x8 r;
    r[0] = (__bf16)u.x; r[1] = (__bf16)u.y; r[2] = (__bf16)u.z; r[3] = (__bf16)u.w;
    r[4] = (__bf16)v.x; r[5] = (__bf16)v.y; r[6] = (__bf16)v.z; r[7] = (__bf16)v.w;
    return r;
}

__device__ __forceinline__ float sigm(float x) { return 1.f / (1.f + __expf(-x)); }
// tanh(x) = 1 - 2/(e^{2x}+1); saturates correctly for large |x|
__device__ __forceinline__ float tanh_fast(float x) {
    const float e = __expf(2.f * x);
    return 1.f - 2.f / (e + 1.f);
}
__device__ __forceinline__ unsigned short bfbits(float x) {
    return __builtin_bit_cast(unsigned short, (__bf16)x);
}
__device__ __forceinline__ float us2f(unsigned short u) {
    return __builtin_bit_cast(float, (unsigned)u << 16);
}

// ---------------- setup: zero flags, build initial h (fwd=0, bwd=bh0) -------
__global__ void k_setup(const float* __restrict__ bh0,
                        __bf16* __restrict__ hinit, int* __restrict__ flags) {
    const int tid = blockIdx.x * 256 + threadIdx.x;
    if (tid < 256) flags[tid] = 0;
    if (tid < Bb * Hh) {
        hinit[tid] = (__bf16)0.f;
        hinit[Bb * Hh + tid] = (__bf16)bh0[tid & (Hh - 1)];
    }
}

// ---------------- one-time Wh f32 -> bf16, layout [4][512 hcol][512 k] -------
__global__ __launch_bounds__(256) void k_wcvt(
    const float* __restrict__ Wf, const float* __restrict__ Wi,
    const float* __restrict__ Wo, const float* __restrict__ Wc,
    __bf16* __restrict__ Whb)
{
    const int e = (blockIdx.x * 256 + threadIdx.x) * 4;   // 4 elems/thread
    const int g = e >> 18;
    const int rem = e & 262143;
    const int hr = rem >> 9;            // gate row (h col)
    const int k  = rem & 511;           // recurrent k
    const float* W = (g == 0) ? Wf : (g == 1) ? Wi : (g == 2) ? Wo : Wc;
    const float4 v = *reinterpret_cast<const float4*>(W + (long)hr * 768 + Ii + k);
    unsigned short s0 = bfbits(v.x), s1 = bfbits(v.y), s2 = bfbits(v.z), s3 = bfbits(v.w);
    uint2 pk;
    pk.x = ((unsigned)s1 << 16) | s0;
    pk.y = ((unsigned)s3 << 16) | s2;
    *reinterpret_cast<uint2*>(Whb + e) = pk;
}

// ---------------- xproj = x @ Wx^T + b  -> [T][B][4H] bf16 -------------------
__global__ __launch_bounds__(256) void k_xproj(
    const float* __restrict__ x,
    const float* __restrict__ Wf, const float* __restrict__ bf_,
    const float* __restrict__ Wi, const float* __restrict__ bi_,
    const float* __restrict__ Wo, const float* __restrict__ bo_,
    const float* __restrict__ Wc, const float* __restrict__ bc_,
    __bf16* __restrict__ xproj)
{
    const int wgM = blockIdx.x;           // 0..255  (64 rows each)
    const int wgN = blockIdx.y;           // 0..15   (128 cols each)
    const int tid = threadIdx.x;
    const int wave = tid >> 6, lane = tid & 63;
    const int mw = wave >> 1, nw = wave & 1;
    const int l15 = lane & 15, lhi = lane >> 4;

    const int gamma = wgN >> 2;           // whole wg in one gate (128 | 512)
    const float* W    = (gamma == 0) ? Wf : (gamma == 1) ? Wi : (gamma == 2) ? Wo : Wc;
    const float* bptr = (gamma == 0) ? bf_ : (gamma == 1) ? bi_ : (gamma == 2) ? bo_ : bc_;

    f32x4 acc[2][4];
#pragma unroll
    for (int m = 0; m < 2; m++)
#pragma unroll
        for (int n = 0; n < 4; n++) acc[m][n] = f32x4{0.f, 0.f, 0.f, 0.f};

    const int rowbase = wgM * 64 + mw * 32;
    const int colbase = wgN * 128 + nw * 64;

#pragma unroll
    for (int kk = 0; kk < 8; ++kk) {
        const int k0 = kk * 32 + lhi * 8;
        bf16x8 a[2], b[4];
#pragma unroll
        for (int m = 0; m < 2; m++) {
            const int r = rowbase + m * 16 + l15;        // x row = b*T + t
            a[m] = f32x8_to_bf16(x + (long)r * Ii + k0);
        }
#pragma unroll
        for (int n = 0; n < 4; n++) {
            const int g = colbase + n * 16 + l15;
            b[n] = f32x8_to_bf16(W + (long)(g & 511) * 768 + k0);
        }
#pragma unroll
        for (int m = 0; m < 2; m++)
#pragma unroll
            for (int n = 0; n < 4; n++)
                acc[m][n] = __builtin_amdgcn_mfma_f32_16x16x32_bf16(a[m], b[n], acc[m][n], 0, 0, 0);
    }

#pragma unroll
    for (int m = 0; m < 2; m++)
#pragma unroll
        for (int n = 0; n < 4; n++) {
            const int g = colbase + n * 16 + l15;
            const float bias = bptr[g & 511];
#pragma unroll
            for (int r = 0; r < 4; r++) {
                const int R = rowbase + m * 16 + lhi * 4 + r;   // = b*T + t
                const int t = R & (Tt - 1), bb = R >> 9;
                xproj[((long)t * Bb + bb) * 2048 + g] = (__bf16)(acc[m][n][r] + bias);
            }
        }
}

// ---------------- recurrence: 32 wgs/dir x 256 thr, W in LDS, lane-local cell
__global__ __launch_bounds__(256, 1) void k_rec(
    const __bf16* __restrict__ Whb,    // [4][512][512] bf16
    const float* __restrict__ bc0,
    const __bf16* __restrict__ xproj,  // [T][B][4H]
    __bf16* __restrict__ hs,           // [2][T][B][H]
    const __bf16* __restrict__ hinit,  // [2][B][H]
    int* flags)                        // [2][128]  (32 wg x 4 waves)
{
    const int dir  = blockIdx.x >> 5;
    const int gsel = blockIdx.x & 31;       // owns h-cols [gsel*16, +16)
    const int tid  = threadIdx.x;
    const int wave = tid >> 6;              // 0..3 : 4 h-cols each
    const int lane = tid & 63;
    const int l15  = lane & 15, lhi = lane >> 4;

    __shared__ __bf16 Wlds[64 * 512];       // 64 KiB: rows j = hcol_local*4+gate
    __shared__ __bf16 hb[2][Bb * Hh];       // 2 x 32 KiB, XOR-swizzled h
                                            // (R6 bug: was Bb*Hh/2 -> LDS OOB)

    // one-time: copy this wg's weight slice into LDS (swizzled)
    char* wl = reinterpret_cast<char*>(Wlds);
    for (int c = tid; c < 4096; c += 256) {
        const int row = c >> 6, q = c & 63;        // row 0..63, 16B unit 0..63
        const int gate = row & 3;
        const int hc   = gsel * 16 + (row >> 4) * 4 + ((row & 15) >> 2);
        const bf16x8 w = *reinterpret_cast<const bf16x8*>(
            Whb + (long)(gate * 512 + hc) * 512 + q * 8);
        *reinterpret_cast<bf16x8*>(wl + row * 1024 + ((q * 16) ^ ((row & 7) << 4))) = w;
    }
    // first use is after the s=0 __syncthreads below

    const int hcol = gsel * 16 + wave * 4 + lhi;    // this thread's h column
    float cs0 = (dir == 0) ? 0.f : bc0[hcol];       // batch l15
    float cs1 = cs0;                                // batch 16+l15

    int* flagd = flags + dir * 128;
    __bf16* hsd = hs + (long)dir * Tt * Bb * Hh;

    const char* wbase = wl + (wave * 16 + l15) * 1024;   // A-frag row base
    const int asw = ((wave * 16 + l15) & 7) << 4;
    const int bsw = (l15 & 7) << 4;
    const int srow = tid >> 6;          // staging: rows srow+4j
    const int sck  = tid & 63;          // 16B chunk in row

    for (int s = 0; s < Tt; ++s) {
        const int t = (dir == 0) ? s : (Tt - 1 - s);

        // prefetch this step's xproj gates (8 ushorts; consumed at step end)
        const __bf16* xpb = xproj + (long)t * Bb * 2048 + hcol;
        unsigned short xr0[4], xr1[4];
#pragma unroll
        for (int g = 0; g < 4; ++g) {
            xr0[g] = __builtin_bit_cast(unsigned short, xpb[l15 * 2048 + g * 512]);
            xr1[g] = __builtin_bit_cast(unsigned short, xpb[(16 + l15) * 2048 + g * 512]);
        }

        // every wave polls all 128 producer flags (bounded spin)
        if (s > 0) {
            for (int p = 0; p < 4096; ++p) {
                const int f0 = __hip_atomic_load(flagd + lane, __ATOMIC_RELAXED,
                                                 __HIP_MEMORY_SCOPE_AGENT);
                const int f1 = __hip_atomic_load(flagd + 64 + lane, __ATOMIC_RELAXED,
                                                 __HIP_MEMORY_SCOPE_AGENT);
                if (__all(f0 >= s && f1 >= s)) break;
                __builtin_amdgcn_s_sleep(1);
            }
        }

        // stage h_{s-1} -> hb[s&1] (coherent loads, 16B XOR swizzle)
        const __bf16* hp = (s == 0) ? (hinit + (long)dir * Bb * Hh)
                                    : (hsd + (long)((dir == 0) ? (t - 1) : (t + 1)) * Bb * Hh);
        const char* gb0 = reinterpret_cast<const char*>(hp) + srow * 1024 + sck * 16;
        f32x4 v0, v1, v2, v3, v4, v5, v6, v7;
#define LDC(i, dst) asm volatile("global_load_dwordx4 %0, %1, off sc0 sc1" \
                                 : "=&v"(dst) : "v"(gb0 + (i) * 4096) : "memory")
        LDC(0, v0); LDC(1, v1); LDC(2, v2); LDC(3, v3);
        LDC(4, v4); LDC(5, v5); LDC(6, v6); LDC(7, v7);
#undef LDC
        asm volatile("s_waitcnt vmcnt(0)" ::: "memory");
        __builtin_amdgcn_sched_barrier(0);
        char* hc = reinterpret_cast<char*>(hb[s & 1]);
#define STC(i, src) { const int r = srow + 4 * (i); \
        *reinterpret_cast<f32x4*>(hc + r * 1024 + ((sck * 16) ^ ((r & 7) << 4))) = src; }
        STC(0, v0); STC(1, v1); STC(2, v2); STC(3, v3);
        STC(4, v4); STC(5, v5); STC(6, v6); STC(7, v7);
#undef STC
        __syncthreads();    // the only barrier per step (hb double-buffered)

        // C[j][b] = sum_k W[j][k] * h[b][k] : j = hcol_local*4+gate, b = batch
        f32x4 acc0 = f32x4{0.f, 0.f, 0.f, 0.f};    // batches 0..15
        f32x4 acc1 = f32x4{0.f, 0.f, 0.f, 0.f};    // batches 16..31
#pragma unroll
        for (int kk = 0; kk < 16; ++kk) {
            const int kb = kk * 64 + lhi * 16;
            const bf16x8 af = *reinterpret_cast<const bf16x8*>(wbase + (kb ^ asw));
            const bf16x8 b0 = *reinterpret_cast<const bf16x8*>(
                hc + l15 * 1024 + (kb ^ bsw));
            const bf16x8 b1 = *reinterpret_cast<const bf16x8*>(
                hc + (16 + l15) * 1024 + (kb ^ bsw));
            acc0 = __builtin_amdgcn_mfma_f32_16x16x32_bf16(af, b0, acc0, 0, 0, 0);
            acc1 = __builtin_amdgcn_mfma_f32_16x16x32_bf16(af, b1, acc1, 0, 0, 0);
        }

        // cell update straight out of the accumulator (acc[reg] = gate reg)
        float hv0, hv1;
        {
            const float gf = us2f(xr0[0]) + acc0[0];
            const float gi = us2f(xr0[1]) + acc0[1];
            const float go = us2f(xr0[2]) + acc0[2];
            const float gc = us2f(xr0[3]) + acc0[3];
            cs0 = sigm(gf) * cs0 + sigm(gi) * tanh_fast(gc);
            hv0 = sigm(go) * tanh_fast(cs0);
        }
        {
            const float gf = us2f(xr1[0]) + acc1[0];
            const float gi = us2f(xr1[1]) + acc1[1];
            const float go = us2f(xr1[2]) + acc1[2];
            const float gc = us2f(xr1[3]) + acc1[3];
            cs1 = sigm(gf) * cs1 + sigm(gi) * tanh_fast(gc);
            hv1 = sigm(go) * tanh_fast(cs1);
        }
        const unsigned u0 = bfbits(hv0), u1 = bfbits(hv1);
        char* d0 = reinterpret_cast<char*>(hsd + ((long)t * Bb + l15) * Hh + hcol);
        char* d1 = reinterpret_cast<char*>(hsd + ((long)t * Bb + 16 + l15) * Hh + hcol);
        asm volatile("global_store_short %0, %1, off sc0 sc1" :: "v"(d0), "v"(u0) : "memory");
        asm volatile("global_store_short %0, %1, off sc0 sc1" :: "v"(d1), "v"(u1) : "memory");
        asm volatile("s_waitcnt vmcnt(0)" ::: "memory");   // this wave's h at LLC
        if (lane == 0)
            __hip_atomic_store(flagd + gsel * 4 + wave, s + 1, __ATOMIC_RELAXED,
                               __HIP_MEMORY_SCOPE_AGENT);
    }
}

// ---------------- out = cat(hf,hb) @ out_w^T + out_b -> [B][T][O] fp32 -------
__global__ __launch_bounds__(256) void k_out(
    const __bf16* __restrict__ hs,
    const float* __restrict__ out_w,
    const float* __restrict__ out_b,
    float* __restrict__ out)
{
    const int wgM = blockIdx.x;            // 0..255 (64 hs-rows each)
    const int tid = threadIdx.x;
    const int wave = tid >> 6, lane = tid & 63;
    const int mw = wave >> 1, nw = wave & 1;
    const int l15 = lane & 15, lhi = lane >> 4;

    f32x4 acc[2][4];
#pragma unroll
    for (int m = 0; m < 2; m++)
#pragma unroll
        for (int n = 0; n < 4; n++) acc[m][n] = f32x4{0.f, 0.f, 0.f, 0.f};

    const int rowbase = wgM * 64 + mw * 32;   // hs row = t*B + b
    const int colbase = nw * 64;

#pragma unroll 4
    for (int kk = 0; kk < 32; ++kk) {
        const int k0 = kk * 32 + lhi * 8;     // 0..1023
        const int d = k0 >> 9, hk = k0 & 511;
        bf16x8 a[2], b[4];
#pragma unroll
        for (int m = 0; m < 2; m++) {
            const int R = rowbase + m * 16 + l15;
            a[m] = *reinterpret_cast<const bf16x8*>(hs + ((long)d * 16384 + R) * 512 + hk);
        }
#pragma unroll
        for (int n = 0; n < 4; n++) {
            const int o = colbase + n * 16 + l15;
            b[n] = f32x8_to_bf16(out_w + (long)o * 1024 + k0);
        }
#pragma unroll
        for (int m = 0; m < 2; m++)
#pragma unroll
            for (int n = 0; n < 4; n++)
                acc[m][n] = __builtin_amdgcn_mfma_f32_16x16x32_bf16(a[m], b[n], acc[m][n], 0, 0, 0);
    }

#pragma unroll
    for (int m = 0; m < 2; m++)
#pragma unroll
        for (int n = 0; n < 4; n++) {
            const int o = colbase + n * 16 + l15;
            const float bias = out_b[o];
#pragma unroll
            for (int r = 0; r < 4; r++) {
                const int R = rowbase + m * 16 + lhi * 4 + r;   // t*32 + b
                const int tt = R >> 5, bb = R & 31;
                out[((long)bb * Tt + tt) * Oo + o] = acc[m][n][r] + bias;
            }
        }
}

// ---------------- launcher ---------------------------------------------------
extern "C" void kernel_launch(void* const* d_in, const int* in_sizes, int n_in,
                              void* d_out, int out_size, void* d_ws, size_t ws_size,
                              hipStream_t stream) {
    (void)in_sizes; (void)n_in; (void)out_size; (void)ws_size;
    const float* x    = (const float*)d_in[0];
    const float* Wf_w = (const float*)d_in[1];
    const float* Wf_b = (const float*)d_in[2];
    const float* Wi_w = (const float*)d_in[3];
    const float* Wi_b = (const float*)d_in[4];
    const float* Wo_w = (const float*)d_in[5];
    const float* Wo_b = (const float*)d_in[6];
    const float* Wc_w = (const float*)d_in[7];
    const float* Wc_b = (const float*)d_in[8];
    const float* out_w = (const float*)d_in[9];
    const float* out_b = (const float*)d_in[10];
    const float* bh0  = (const float*)d_in[11];
    const float* bc0  = (const float*)d_in[12];

    char* ws = (char*)d_ws;
    __bf16* xproj = (__bf16*)(ws);                       // 67108864 B
    __bf16* hs    = (__bf16*)(ws + 67108864);            // 33554432 B
    __bf16* hinit = (__bf16*)(ws + 100663296);           // 65536 B
    __bf16* Whb   = (__bf16*)(ws + 100728832);           // 2097152 B
    int*    flags = (int*)   (ws + 102825984);           // 1024 B

    k_setup<<<64, 256, 0, stream>>>(bh0, hinit, flags);
    k_wcvt<<<1024, 256, 0, stream>>>(Wf_w, Wi_w, Wo_w, Wc_w, Whb);
    dim3 g1(256, 16);
    k_xproj<<<g1, 256, 0, stream>>>(x, Wf_w, Wf_b, Wi_w, Wi_b, Wo_w, Wo_b, Wc_w, Wc_b, xproj);
    k_rec<<<2 * NG, 256, 0, stream>>>(Whb, bc0, xproj, hs, hinit, flags);
    k_out<<<256, 256, 0, stream>>>(hs, out_w, out_b, (float*)d_out);
}